// Round 1
// 945.209 us; speedup vs baseline: 1.1742x; 1.1742x over previous
//
#include <hip/hip_runtime.h>

// ST_GCNA: 3-head GAT, b=16384, N=22, F=H=192.
// R2: all-MFMA design. e_src/e_dst folded into GEMM as extra B-tile (cols =
// W@a_src, W@a_dst). att@Wh done with MFMA (Wh stored transposed bf16 in LDS).
// Output-head GEMM accumulated in registers across heads (no hcat buffer).
// R3 (this round): VALU diet. (1) ELU via __expf(v)-1 instead of expm1f
// libcall (~20 ops -> ~4). (2) v_cvt_pk_bf16_f32 for all paired f32->bf16
// conversions (staging, storeD, softmax pack, Ah epilogue). (3) wave-parallel
// masked softmax: 8 lanes/row x 22 rows, shfl_xor width-8 reduce (was 22
// serial threads, ~250 instr each).

typedef __attribute__((ext_vector_type(8))) short s16x8;
typedef __attribute__((ext_vector_type(4))) short s16x4;
typedef __attribute__((ext_vector_type(2))) int i32x2;
typedef __attribute__((ext_vector_type(4))) float f32x4;

constexpr int NN = 22;
constexpr int FF = 192;
constexpr int AS = 200;   // stride (shorts) for As1/Ah row-major A buffers
constexpr int TS = 40;    // stride (shorts) for attA rows / WhT cols

__device__ __forceinline__ short f2bf(float f) {
  union { float f; unsigned u; } v; v.f = f;
  unsigned r = v.u + 0x7FFFu + ((v.u >> 16) & 1u);  // RNE
  return (short)(r >> 16);
}

// packed f32x2 -> bf16x2 (RNE), one VALU instruction. lo -> bits[15:0].
__device__ __forceinline__ int cvt_pk_bf16(float lo, float hi) {
  int r;
  asm("v_cvt_pk_bf16_f32 %0, %1, %2" : "=v"(r) : "v"(lo), "v"(hi));
  return r;
}

// cheap ELU: exp(v)-1 for v<0. |err| ~1e-7 abs, fine vs bf16 pipeline.
__device__ __forceinline__ float elu1(float v) {
  float e = __expf(v) - 1.0f;
  return v > 0.f ? v : e;
}

// ---- prep 1: w-vectors  w_src = W @ a[:192], w_dst = W @ a[192:384] ----
// vecs layout (floats): [0:192) w1s [192:384) w1d [384:576) w2s [576:768) w2d
//                       [768:1152) wos [1152:1536) wod
__global__ void prep_vec(const float* __restrict__ W1, const float* __restrict__ a1,
                         const float* __restrict__ W2, const float* __restrict__ a2,
                         const float* __restrict__ Wo, const float* __restrict__ ao,
                         float* __restrict__ vecs) {
  int t = blockIdx.x * 256 + threadIdx.x;
  if (t >= 1536) return;
  const float* W; const float* a; int k;
  if (t < 384)      { W = W1; k = t % 192;            a = a1 + (t / 192) * 192; }
  else if (t < 768) { int u = t - 384; W = W2; k = u % 192; a = a2 + (u / 192) * 192; }
  else              { int u = t - 768; W = Wo; k = u % 384; a = ao + (u / 384) * 192; }
  float s = 0.f;
  for (int o = 0; o < 192; ++o) s += W[k * 192 + o] * a[o];
  vecs[t] = s;
}

// ---- prep 2: pack W1,W2,Wo into bf16 B-fragment-major + extra e-tile ----
// frag elem idx = ((nt*ksteps + ks)*64 + lane)*8 + j ; lane holds B[k][n],
// n = nt*16 + (lane&15), k = ks*32 + (lane>>4)*8 + j. Tile 12: col0=w_src,
// col1=w_dst, rest 0. W1f @0 (39936 sh), W2f @39936, Wof @79872 (79872 sh).
__global__ void prep_pack(const float* __restrict__ W1, const float* __restrict__ W2,
                          const float* __restrict__ Wo, const float* __restrict__ vecs,
                          short* __restrict__ dst) {
  int idx = blockIdx.x * 256 + threadIdx.x;   // grid 624*256 = 159744 exact
  const float* W; int off, ksteps, v0, v1;
  if (idx < 39936)      { W = W1; off = 0;     ksteps = 6;  v0 = 0;   v1 = 192;  }
  else if (idx < 79872) { W = W2; off = 39936; ksteps = 6;  v0 = 384; v1 = 576;  }
  else                  { W = Wo; off = 79872; ksteps = 12; v0 = 768; v1 = 1152; }
  int local = idx - off;
  int j = local & 7, l = (local >> 3) & 63, fi = local >> 9;
  int nt = fi / ksteps, ks = fi - nt * ksteps;
  int k = ks * 32 + ((l >> 4) << 3) + j;
  int nl = l & 15;
  float v;
  if (nt < 12) v = W[k * 192 + nt * 16 + nl];
  else         v = (nl == 0) ? vecs[v0 + k] : (nl == 1) ? vecs[v1 + k] : 0.f;
  dst[idx] = f2bf(v);
}

struct Accs { f32x4 a[2][3]; f32x4 e[2]; };

__device__ __forceinline__ void zacc(Accs& a) {
  #pragma unroll
  for (int m = 0; m < 2; ++m) {
    #pragma unroll
    for (int t = 0; t < 3; ++t) a.a[m][t] = (f32x4){0.f, 0.f, 0.f, 0.f};
    a.e[m] = (f32x4){0.f, 0.f, 0.f, 0.f};
  }
}

// GEMM over 6 ksteps (K=192 slice): A [32][K] bf16 LDS, B frag-major global.
// Waves own n-tiles {3w..3w+2}; wave 3 also the e-tile (tile 12).
__device__ __attribute__((always_inline)) inline void gemm6(
    const short* A, const s16x8* __restrict__ B, int ksTot, int ksOff,
    Accs& ac, int m0, int kg, int wave, int lane) {
  for (int ks = 0; ks < 6; ++ks) {
    const short* ap = A + ks * 32 + kg * 8;
    s16x8 av0 = *(const s16x8*)(ap + m0 * AS);
    s16x8 av1 = *(const s16x8*)(ap + (m0 + 16) * AS);
    #pragma unroll
    for (int t = 0; t < 3; ++t) {
      s16x8 bv = B[((wave * 3 + t) * ksTot + ksOff + ks) * 64 + lane];
      ac.a[0][t] = __builtin_amdgcn_mfma_f32_16x16x32_bf16(av0, bv, ac.a[0][t], 0, 0, 0);
      ac.a[1][t] = __builtin_amdgcn_mfma_f32_16x16x32_bf16(av1, bv, ac.a[1][t], 0, 0, 0);
    }
    if (wave == 3) {
      s16x8 bv = B[(12 * ksTot + ksOff + ks) * 64 + lane];
      ac.e[0] = __builtin_amdgcn_mfma_f32_16x16x32_bf16(av0, bv, ac.e[0], 0, 0, 0);
      ac.e[1] = __builtin_amdgcn_mfma_f32_16x16x32_bf16(av1, bv, ac.e[1], 0, 0, 0);
    }
  }
}

// D -> WhT (bf16, transposed: WhT[col*TS + row]) + es/ed from e-tile.
// Pad D rows 22..31 are exact zeros (A pad rows zeroed) so unconditional
// writes keep WhT pad rows zero -> no 0*garbage NaNs in the PV MFMA.
__device__ __attribute__((always_inline)) inline void storeD(
    const Accs& ac, short* WhTp, float* esp, float* edp, int m0, int kg, int wave) {
  #pragma unroll
  for (int m = 0; m < 2; ++m)
    #pragma unroll
    for (int t = 0; t < 3; ++t) {
      int col = (wave * 3 + t) * 16 + m0;
      int row0 = m * 16 + kg * 4;
      i32x2 p = { cvt_pk_bf16(ac.a[m][t][0], ac.a[m][t][1]),
                  cvt_pk_bf16(ac.a[m][t][2], ac.a[m][t][3]) };
      *(i32x2*)&WhTp[col * TS + row0] = p;   // ds_write_b64
    }
  if (wave == 3 && m0 < 2) {
    float* dst = m0 ? edp : esp;
    #pragma unroll
    for (int m = 0; m < 2; ++m) {
      int row0 = m * 16 + kg * 4;
      #pragma unroll
      for (int r = 0; r < 4; ++r)
        if (row0 + r < NN) dst[row0 + r] = ac.e[m][r];
    }
  }
}

// wave-parallel masked softmax: 8 lanes per row, rows 0..21 -> threads 0..175.
// Each lane owns cols {jl, jl+8, jl+16}; width-8 shfl_xor reduce for max/sum.
// Writes attA row i cols 0..31 (cols >=22 zeroed; pad rows 22..31 untouched,
// garbage there only feeds discarded D rows).
__device__ __forceinline__ void softmax22(
    const float* es, const float* ed, const unsigned* adjm, short* attA, int tid) {
  int i = tid >> 3, jl = tid & 7;
  if (i >= NN) return;
  unsigned msk = adjm[i];
  float esi = es[i];
  float pv[3]; float mx = -3e38f;
  #pragma unroll
  for (int c = 0; c < 3; ++c) {
    int j = jl + 8 * c;
    int jc = j < NN ? j : 0;
    float e = esi + ed[jc];
    e = e > 0.f ? e : 0.2f * e;
    bool live = (j < NN) && ((msk >> j) & 1u);
    pv[c] = live ? e : -9e15f;
    mx = fmaxf(mx, pv[c]);
  }
  #pragma unroll
  for (int d = 1; d < 8; d <<= 1) mx = fmaxf(mx, __shfl_xor(mx, d, 8));
  float s = 0.f;
  #pragma unroll
  for (int c = 0; c < 3; ++c) { float q = __expf(pv[c] - mx); pv[c] = q; s += q; }
  #pragma unroll
  for (int d = 1; d < 8; d <<= 1) s += __shfl_xor(s, d, 8);
  float inv = 1.f / s;
  #pragma unroll
  for (int c = 0; c < 3; ++c) {
    int j = jl + 8 * c;
    if (j < 24) attA[i * TS + j] = (j < NN) ? f2bf(pv[c] * inv) : (short)0;
  }
  attA[i * TS + 24 + jl] = 0;   // cols 24..31
}

// P @ Wh via MFMA: A = attA (bf16 row-major [32][32], zero pad cols),
// B = WhT (bf16 col-major). K=32 single step, 3 n-tiles per wave.
__device__ __attribute__((always_inline)) inline void pv22(
    const short* attAp, const short* WhTp, f32x4 pa[2][3], int m0, int kg, int wave) {
  s16x8 av0 = *(const s16x8*)(attAp + m0 * TS + kg * 8);
  s16x8 av1 = *(const s16x8*)(attAp + (m0 + 16) * TS + kg * 8);
  #pragma unroll
  for (int t = 0; t < 3; ++t) {
    int col = (wave * 3 + t) * 16 + m0;
    s16x8 bv = *(const s16x8*)(WhTp + col * TS + kg * 8);
    pa[0][t] = __builtin_amdgcn_mfma_f32_16x16x32_bf16(av0, bv, pa[0][t], 0, 0, 0);
    pa[1][t] = __builtin_amdgcn_mfma_f32_16x16x32_bf16(av1, bv, pa[1][t], 0, 0, 0);
  }
}

__global__ __launch_bounds__(256, 3) void gat_main(
    const float* __restrict__ x, const float* __restrict__ adj,
    const short* __restrict__ wsb, float* __restrict__ out) {
  __shared__ __align__(16) short As1[32 * AS];   // x bf16, rows 22..31 zeroed
  __shared__ __align__(16) short Ah [32 * AS];   // per-head output bf16, pad zeroed
  __shared__ __align__(16) short attA[32 * TS];  // att bf16 A-layout
  __shared__ __align__(16) short WhT[FF * TS];   // Wh^T bf16 (B-operand layout)
  __shared__ float es[NN], ed[NN];
  __shared__ unsigned adjm[NN];

  const int tid = threadIdx.x, lane = tid & 63, wave = tid >> 6;
  const int m0 = lane & 15, kg = (lane >> 4) & 3;
  const size_t b = blockIdx.x;
  const float* xb = x + b * (size_t)(NN * FF);

  // stage x -> bf16 LDS (float4 loads, cvt_pk, b64 LDS writes)
  for (int i4 = tid; i4 < 1056; i4 += 256) {
    int row = i4 / 48, c = (i4 - row * 48) * 4;
    float4 v = ((const float4*)xb)[i4];
    i32x2 p = { cvt_pk_bf16(v.x, v.y), cvt_pk_bf16(v.z, v.w) };
    *(i32x2*)&As1[row * AS + c] = p;
  }
  { // zero pad rows 22..31 of As1 and Ah (keeps all D pad rows finite zero)
    int* z1 = (int*)(As1 + NN * AS);
    int* z2 = (int*)(Ah + NN * AS);
    for (int i = tid; i < 1000; i += 256) { z1[i] = 0; z2[i] = 0; }
  }
  if (tid < NN) {  // adjacency bitmask
    unsigned m = 0;
    for (int j = 0; j < NN; ++j) m |= (adj[tid * NN + j] > 0.f ? 1u : 0u) << j;
    adjm[tid] = m;
  }
  __syncthreads();

  const s16x8* BW  = (const s16x8*)wsb;          // W1f frags
  const s16x8* BWo = (const s16x8*)wsb + 9984;   // Wof frags

  Accs aco; zacc(aco);                            // persistent Wh_o accumulator

  for (int h = 0; h < 2; ++h) {
    // GEMM: Wh = x @ W_h (+ e-tile) -> WhT bf16, es/ed fp32
    Accs ach; zacc(ach);
    gemm6(As1, BW + h * 4992, 6, 0, ach, m0, kg, wave, lane);
    storeD(ach, WhT, es, ed, m0, kg, wave);
    __syncthreads();

    // masked softmax rows -> attA bf16 (cols 22..31 zeroed)
    softmax22(es, ed, adjm, attA, tid);
    __syncthreads();

    // out_h = elu(att @ Wh) -> Ah bf16
    f32x4 pa[2][3];
    #pragma unroll
    for (int m = 0; m < 2; ++m)
      #pragma unroll
      for (int t = 0; t < 3; ++t) pa[m][t] = (f32x4){0.f, 0.f, 0.f, 0.f};
    pv22(attA, WhT, pa, m0, kg, wave);
    #pragma unroll
    for (int m = 0; m < 2; ++m)
      #pragma unroll
      for (int t = 0; t < 3; ++t) {
        int col = (wave * 3 + t) * 16 + m0;
        int row0 = m * 16 + kg * 4;
        float v0 = elu1(pa[m][t][0]), v1 = elu1(pa[m][t][1]);
        float v2 = elu1(pa[m][t][2]), v3 = elu1(pa[m][t][3]);
        int qa = cvt_pk_bf16(v0, v1), qb = cvt_pk_bf16(v2, v3);
        if (row0 < NN)     Ah[row0 * AS + col]       = (short)qa;
        if (row0 + 1 < NN) Ah[(row0 + 1) * AS + col] = (short)(qa >> 16);
        if (row0 + 2 < NN) Ah[(row0 + 2) * AS + col] = (short)qb;
        if (row0 + 3 < NN) Ah[(row0 + 3) * AS + col] = (short)(qb >> 16);
      }
    __syncthreads();

    // accumulate Wh_o += h_h @ Wo[h*192:(h+1)*192, :] (+ e-tile) in registers
    gemm6(Ah, BWo, 12, 6 * h, aco, m0, kg, wave, lane);
  }

  // output head
  storeD(aco, WhT, es, ed, m0, kg, wave);
  __syncthreads();
  softmax22(es, ed, adjm, attA, tid);
  __syncthreads();

  f32x4 pa[2][3];
  #pragma unroll
  for (int m = 0; m < 2; ++m)
    #pragma unroll
    for (int t = 0; t < 3; ++t) pa[m][t] = (f32x4){0.f, 0.f, 0.f, 0.f};
  pv22(attA, WhT, pa, m0, kg, wave);
  float* ob = out + b * (size_t)(NN * FF);
  #pragma unroll
  for (int m = 0; m < 2; ++m)
    #pragma unroll
    for (int t = 0; t < 3; ++t) {
      int col = (wave * 3 + t) * 16 + m0;
      int row0 = m * 16 + kg * 4;
      #pragma unroll
      for (int r = 0; r < 4; ++r) {
        int row = row0 + r;
        if (row < NN) {
          float v = elu1(pa[m][t][r]);
          ob[row * FF + col] = v + xb[row * FF + col];
        }
      }
    }
}

extern "C" void kernel_launch(void* const* d_in, const int* in_sizes, int n_in,
                              void* d_out, int out_size, void* d_ws, size_t ws_size,
                              hipStream_t stream) {
  const float* x   = (const float*)d_in[0];
  const float* adj = (const float*)d_in[1];
  const float* W1  = (const float*)d_in[2];
  const float* a1  = (const float*)d_in[3];
  const float* W2  = (const float*)d_in[4];
  const float* a2  = (const float*)d_in[5];
  const float* Wo  = (const float*)d_in[6];
  const float* ao  = (const float*)d_in[7];
  float* out = (float*)d_out;
  short* wsb  = (short*)d_ws;                        // 319488 B frags
  float* vecs = (float*)((char*)d_ws + 319488);      // + 6144 B w-vectors

  const int batch = in_sizes[0] / (NN * FF);         // 16384
  prep_vec <<<6,   256, 0, stream>>>(W1, a1, W2, a2, Wo, ao, vecs);
  prep_pack<<<624, 256, 0, stream>>>(W1, W2, Wo, vecs, wsb);
  gat_main <<<batch, 256, 0, stream>>>(x, adj, wsb, out);
}